// Round 1
// baseline (609.383 us; speedup 1.0000x reference)
//
#include <hip/hip_runtime.h>
#include <math.h>

#define NE 8192
#define CDIM 64
#define NPIX 32768
#define HWSZ 4096
#define BIMG (CDIM * HWSZ) /* 262144 floats per batch image */
#define NCHUNK 8
#define CPC (NE / NCHUNK) /* 1024 codes per chunk */
#define TILE 128
#define BLK 256

// ---------------- Kernel A: esq[k] = sum(e[k]^2) replicating numpy pairwise order --------
__global__ __launch_bounds__(256) void esq_kernel(const float* __restrict__ emb,
                                                  float* __restrict__ esq) {
    int k = blockIdx.x * 256 + threadIdx.x;
    const float4* e4 = (const float4*)(emb + (long)k * CDIM);
    float er[CDIM];
#pragma unroll
    for (int i = 0; i < 16; ++i) {
        float4 v = e4[i];
        er[4 * i + 0] = v.x; er[4 * i + 1] = v.y;
        er[4 * i + 2] = v.z; er[4 * i + 3] = v.w;
    }
    float res;
    {
#pragma clang fp contract(off)
        float r[8];
#pragma unroll
        for (int j = 0; j < 8; ++j) r[j] = er[j] * er[j];
#pragma unroll
        for (int i = 8; i < CDIM; i += 8) {
#pragma unroll
            for (int j = 0; j < 8; ++j) r[j] += er[i + j] * er[i + j];
        }
        res = ((r[0] + r[1]) + (r[2] + r[3])) + ((r[4] + r[5]) + (r[6] + r[7]));
    }
    esq[k] = res;
}

// ---------------- Kernel B: per (pixel, code-chunk) argmin of fp32 distances -------------
__global__ __launch_bounds__(BLK, 4) void dist_kernel(const float* __restrict__ z,
                                                      const float* __restrict__ emb,
                                                      const float* __restrict__ esq,
                                                      float* __restrict__ part_d,
                                                      int* __restrict__ part_i) {
    __shared__ __align__(16) float e_tile[TILE * CDIM];
    __shared__ float esq_tile[TILE];

    const int tid = threadIdx.x;
    const int pix = blockIdx.x * BLK + tid;
    const int chunk = blockIdx.y;
    const int b = pix >> 12;          // 4096 pixels per batch image
    const int hw = pix & (HWSZ - 1);

    // Load this pixel's channel vector (stride HWSZ -> coalesced across lanes per c)
    const float* zp = z + (long)b * BIMG + hw;
    float zr[CDIM];
#pragma unroll
    for (int c = 0; c < CDIM; ++c) zr[c] = zp[c * HWSZ];

    // zsq replicating numpy pairwise sum of the squared array (no fma contraction)
    float zsq;
    {
#pragma clang fp contract(off)
        float r[8];
#pragma unroll
        for (int j = 0; j < 8; ++j) r[j] = zr[j] * zr[j];
#pragma unroll
        for (int i = 8; i < CDIM; i += 8) {
#pragma unroll
            for (int j = 0; j < 8; ++j) r[j] += zr[i + j] * zr[i + j];
        }
        zsq = ((r[0] + r[1]) + (r[2] + r[3])) + ((r[4] + r[5]) + (r[6] + r[7]));
    }

    const int code_base = chunk * CPC;
    float best_d = INFINITY;
    int best_i = code_base;

    for (int t0 = 0; t0 < CPC; t0 += TILE) {
        __syncthreads();
        // Stage TILE codes (TILE*CDIM floats = 2048 float4) cooperatively
        const float4* src = (const float4*)(emb + (long)(code_base + t0) * CDIM);
        float4* dst = (float4*)e_tile;
#pragma unroll
        for (int i = 0; i < (TILE * CDIM / 4) / BLK; ++i)
            dst[i * BLK + tid] = src[i * BLK + tid];
        if (tid < TILE) esq_tile[tid] = esq[code_base + t0 + tid];
        __syncthreads();

#pragma unroll 2
        for (int c = 0; c < TILE; ++c) {
            const float4* ev = (const float4*)(e_tile + c * CDIM);
            float d0 = 0.f, d1 = 0.f, d2 = 0.f, d3 = 0.f;
#pragma unroll
            for (int q = 0; q < 16; ++q) {
                float4 e4 = ev[q];  // uniform address -> LDS broadcast, conflict-free
                d0 = fmaf(zr[4 * q + 0], e4.x, d0);
                d1 = fmaf(zr[4 * q + 1], e4.y, d1);
                d2 = fmaf(zr[4 * q + 2], e4.z, d2);
                d3 = fmaf(zr[4 * q + 3], e4.w, d3);
            }
            float dot = (d0 + d1) + (d2 + d3);
            float t1 = zsq + esq_tile[c];     // fp32 round (matches numpy broadcast add)
            float dist = t1 - 2.0f * dot;     // 2*dot exact; single round
            if (dist < best_d) { best_d = dist; best_i = code_base + t0 + c; }
        }
    }
    part_d[chunk * NPIX + pix] = best_d;
    part_i[chunk * NPIX + pix] = best_i;
}

// ---------------- Kernel C: merge chunks, gather, write z_q + indices, partial loss ------
__global__ __launch_bounds__(BLK) void finalize_kernel(const float* __restrict__ z,
                                                       const float* __restrict__ emb,
                                                       const float* __restrict__ part_d,
                                                       const int* __restrict__ part_i,
                                                       float* __restrict__ out,
                                                       float* __restrict__ block_loss) {
    const int tid = threadIdx.x;
    const int pix = blockIdx.x * BLK + tid;

    float best_d = part_d[pix];
    int best_i = part_i[pix];
#pragma unroll
    for (int ch = 1; ch < NCHUNK; ++ch) {
        float d = part_d[ch * NPIX + pix];
        int i = part_i[ch * NPIX + pix];
        if (d < best_d) { best_d = d; best_i = i; }  // strict < : lowest index wins
    }

    const int b = pix >> 12;
    const int hw = pix & (HWSZ - 1);
    const float* zp = z + (long)b * BIMG + hw;
    const float* q = emb + (long)best_i * CDIM;
    float* op = out + (long)b * BIMG + hw;

    float lsum = 0.f;
#pragma unroll
    for (int c = 0; c < CDIM; ++c) {
        float zv = zp[c * HWSZ];
        float qv = q[c];
        float diff = qv - zv;          // fp32 round
        op[c * HWSZ] = zv + diff;      // STE: z + (q - z), same roundings as reference
        lsum += diff * diff;           // loss uses (q - z)^2 ; 2% threshold -> any order
    }

    out[(long)NPIX * CDIM + 1 + pix] = (float)best_i;  // indices chunk as fp32

    __shared__ float red[BLK];
    red[tid] = lsum;
    __syncthreads();
    for (int s = BLK / 2; s > 0; s >>= 1) {
        if (tid < s) red[tid] += red[tid + s];
        __syncthreads();
    }
    if (tid == 0) block_loss[blockIdx.x] = red[0];
}

// ---------------- Kernel D: final loss reduction ----------------------------------------
__global__ __launch_bounds__(128) void loss_kernel(const float* __restrict__ block_loss,
                                                   float* __restrict__ out) {
    __shared__ float red[128];
    const int tid = threadIdx.x;
    red[tid] = block_loss[tid];
    __syncthreads();
    for (int s = 64; s > 0; s >>= 1) {
        if (tid < s) red[tid] += red[tid + s];
        __syncthreads();
    }
    if (tid == 0) {
        float m = red[0] * (1.0f / (float)(NPIX * CDIM));
        out[(long)NPIX * CDIM] = m + 0.25f * m;  // mean + beta*mean (identical values)
    }
}

extern "C" void kernel_launch(void* const* d_in, const int* in_sizes, int n_in,
                              void* d_out, int out_size, void* d_ws, size_t ws_size,
                              hipStream_t stream) {
    const float* z = (const float*)d_in[0];
    const float* emb = (const float*)d_in[1];
    float* out = (float*)d_out;

    char* ws = (char*)d_ws;
    float* part_d = (float*)ws;                                   // 1 MB
    int* part_i = (int*)(ws + (long)NCHUNK * NPIX * 4);           // 1 MB
    float* esq = (float*)(ws + 2L * NCHUNK * NPIX * 4);           // 32 KB
    float* block_loss = (float*)(ws + 2L * NCHUNK * NPIX * 4 + NE * 4);  // 512 B

    esq_kernel<<<NE / 256, 256, 0, stream>>>(emb, esq);

    dim3 gridB(NPIX / BLK, NCHUNK);
    dist_kernel<<<gridB, BLK, 0, stream>>>(z, emb, esq, part_d, part_i);

    finalize_kernel<<<NPIX / BLK, BLK, 0, stream>>>(z, emb, part_d, part_i, out, block_loss);

    loss_kernel<<<1, 128, 0, stream>>>(block_loss, out);
}

// Round 2
// 512.286 us; speedup vs baseline: 1.1895x; 1.1895x over previous
//
#include <hip/hip_runtime.h>
#include <math.h>

#define NE 8192
#define CDIM 64
#define NPIX 32768
#define HWSZ 4096
#define BIMG (CDIM * HWSZ)
#define NSUPER 4
#define CPS (NE / NSUPER)   /* 2048 codes per super-chunk */
#define MB 128              /* pixels per block */
#define NTILE 128           /* codes per LDS tile */
#define BLK 256

// ---------------- esq[k] = sum(e[k]^2), numpy pairwise order (proven round 1) ------------
__global__ __launch_bounds__(256) void esq_kernel(const float* __restrict__ emb,
                                                  float* __restrict__ esq) {
    int k = blockIdx.x * 256 + threadIdx.x;
    const float4* e4 = (const float4*)(emb + (long)k * CDIM);
    float er[CDIM];
#pragma unroll
    for (int i = 0; i < 16; ++i) {
        float4 v = e4[i];
        er[4 * i + 0] = v.x; er[4 * i + 1] = v.y;
        er[4 * i + 2] = v.z; er[4 * i + 3] = v.w;
    }
    float res;
    {
#pragma clang fp contract(off)
        float r[8];
#pragma unroll
        for (int j = 0; j < 8; ++j) r[j] = er[j] * er[j];
#pragma unroll
        for (int i = 8; i < CDIM; i += 8) {
#pragma unroll
            for (int j = 0; j < 8; ++j) r[j] += er[i + j] * er[i + j];
        }
        res = ((r[0] + r[1]) + (r[2] + r[3])) + ((r[4] + r[5]) + (r[6] + r[7]));
    }
    esq[k] = res;
}

// ---------------- zsq[pix] = sum(z[pix]^2), identical pairwise order ---------------------
__global__ __launch_bounds__(256) void zsq_kernel(const float* __restrict__ z,
                                                  float* __restrict__ zsq) {
    int pix = blockIdx.x * 256 + threadIdx.x;
    int b = pix >> 12, hw = pix & (HWSZ - 1);
    const float* zp = z + (long)b * BIMG + hw;
    float zr[CDIM];
#pragma unroll
    for (int c = 0; c < CDIM; ++c) zr[c] = zp[c * HWSZ];
    float res;
    {
#pragma clang fp contract(off)
        float r[8];
#pragma unroll
        for (int j = 0; j < 8; ++j) r[j] = zr[j] * zr[j];
#pragma unroll
        for (int i = 8; i < CDIM; i += 8) {
#pragma unroll
            for (int j = 0; j < 8; ++j) r[j] += zr[i + j] * zr[i + j];
        }
        res = ((r[0] + r[1]) + (r[2] + r[3])) + ((r[4] + r[5]) + (r[6] + r[7]));
    }
    zsq[pix] = res;
}

// ---------------- register-tiled distance/argmin GEMM ------------------------------------
// Block: 256 threads (tx 0..15 -> 8 pixels each, ty 0..15 -> 8 codes each per tile).
// zT[k][pix] staged once (32 KB, group-swizzled); eL[code][c] streamed per 128-code tile
// (32 KB, group-swizzled). Each thread: 8x8 fp32 accumulators, K=64 single FMA chain.
__global__ __launch_bounds__(BLK, 2) void dist_kernel(const float* __restrict__ z,
                                                      const float* __restrict__ emb,
                                                      const float* __restrict__ esq,
                                                      const float* __restrict__ zsq,
                                                      float* __restrict__ part_d,
                                                      int* __restrict__ part_i) {
    __shared__ __align__(16) float zT[64 * 128];
    __shared__ __align__(16) float eL[128 * 64];

    const int tid = threadIdx.x;
    const int tx = tid & 15, ty = tid >> 4;
    const int pix0 = blockIdx.x * MB;
    const int b = pix0 >> 12, hw0 = pix0 & (HWSZ - 1);
    const int super = blockIdx.y;
    const int code00 = super * CPS;

    // ---- stage zT (straight copy; z global is already [c][pix]) ----
    {
        const float* zg = z + (long)b * BIMG + hw0;
#pragma unroll
        for (int i = 0; i < 8; ++i) {
            int f = i * BLK + tid;              // 0..2047 float4 slots
            int k = f >> 5, pg = f & 31;        // 32 groups of 4 pixels per row
            int pgs = pg ^ (pg >> 3);           // bank swizzle
            float4 v = *(const float4*)(zg + k * HWSZ + pg * 4);
            *(float4*)(zT + k * 128 + pgs * 4) = v;
        }
    }

    float zs[8];
#pragma unroll
    for (int i = 0; i < 8; ++i) zs[i] = zsq[pix0 + tx * 8 + i];

    // per-thread constant LDS read offsets (post-swizzle)
    const int pgA = 2 * tx, pgB = 2 * tx + 1;
    const int zoffA = (pgA ^ (pgA >> 3)) * 4;
    const int zoffB = (pgB ^ (pgB >> 3)) * 4;
    const int s_e = ty & 7;

    float bd8[8];
    int bi8[8];
#pragma unroll
    for (int i = 0; i < 8; ++i) { bd8[i] = INFINITY; bi8[i] = code00; }

    for (int tile = 0; tile < CPS / NTILE; ++tile) {
        const int code0 = code00 + tile * NTILE;
        __syncthreads();  // previous tile's eL readers done
        // ---- stage eL (straight copy rows, swizzled c-groups) ----
        const float4* eg = (const float4*)(emb + (long)code0 * CDIM);
#pragma unroll
        for (int i = 0; i < 8; ++i) {
            int f = i * BLK + tid;              // 0..2047
            int cc = f >> 4, g = f & 15;        // 16 c-groups per code row
            int gs = g ^ ((cc >> 3) & 7);
            *(float4*)(eL + cc * 64 + gs * 4) = eg[f];
        }
        float esq_t[8];
#pragma unroll
        for (int j = 0; j < 8; ++j) esq_t[j] = esq[code0 + ty * 8 + j];
        __syncthreads();

        float accA[4][8], accB[4][8];
#pragma unroll
        for (int p = 0; p < 4; ++p)
#pragma unroll
            for (int j = 0; j < 8; ++j) { accA[p][j] = 0.f; accB[p][j] = 0.f; }

#pragma unroll 2
        for (int kb = 0; kb < 16; ++kb) {
            float4 za[4], zb[4], ef[8];
#pragma unroll
            for (int kk = 0; kk < 4; ++kk) {
                za[kk] = *(const float4*)(zT + (kb * 4 + kk) * 128 + zoffA);
                zb[kk] = *(const float4*)(zT + (kb * 4 + kk) * 128 + zoffB);
            }
            const int gs = (kb ^ s_e) * 4;
#pragma unroll
            for (int j = 0; j < 8; ++j)
                ef[j] = *(const float4*)(eL + (ty * 8 + j) * 64 + gs);

#pragma unroll
            for (int j = 0; j < 8; ++j) {
                const float* ej = (const float*)&ef[j];
#pragma unroll
                for (int kk = 0; kk < 4; ++kk) {
                    const float ev = ej[kk];
                    const float* zak = (const float*)&za[kk];
                    const float* zbk = (const float*)&zb[kk];
#pragma unroll
                    for (int p = 0; p < 4; ++p) {
                        accA[p][j] = fmaf(zak[p], ev, accA[p][j]);
                        accB[p][j] = fmaf(zbk[p], ev, accB[p][j]);
                    }
                }
            }
        }

        // epilogue: d = (zsq + esq) - 2*dot, exact reference rounding; strict < argmin
#pragma unroll
        for (int j = 0; j < 8; ++j) {
            const int idx = code0 + ty * 8 + j;
#pragma unroll
            for (int p = 0; p < 4; ++p) {
                float t1 = zs[p] + esq_t[j];
                float dist = fmaf(-2.0f, accA[p][j], t1);
                if (dist < bd8[p]) { bd8[p] = dist; bi8[p] = idx; }
            }
#pragma unroll
            for (int p = 0; p < 4; ++p) {
                float t1 = zs[p + 4] + esq_t[j];
                float dist = fmaf(-2.0f, accB[p][j], t1);
                if (dist < bd8[p + 4]) { bd8[p + 4] = dist; bi8[p + 4] = idx; }
            }
        }
    }

    // ---- cross-ty reduction (16 candidates per pixel), tie -> lowest index ----
    __syncthreads();
    float* red_d = eL;                  // [16][128]
    int* red_i = (int*)(eL + 2048);     // [16][128]
#pragma unroll
    for (int p = 0; p < 8; ++p) {
        red_d[ty * 128 + tx * 8 + p] = bd8[p];
        red_i[ty * 128 + tx * 8 + p] = bi8[p];
    }
    __syncthreads();
    if (tid < 128) {
        float bd = red_d[tid];
        int bi = red_i[tid];
#pragma unroll
        for (int t = 1; t < 16; ++t) {
            float d = red_d[t * 128 + tid];
            int i2 = red_i[t * 128 + tid];
            if (d < bd || (d == bd && i2 < bi)) { bd = d; bi = i2; }
        }
        part_d[super * NPIX + pix0 + tid] = bd;
        part_i[super * NPIX + pix0 + tid] = bi;
    }
}

// ---------------- merge supers, gather, STE write, indices, partial loss -----------------
__global__ __launch_bounds__(BLK) void finalize_kernel(const float* __restrict__ z,
                                                       const float* __restrict__ emb,
                                                       const float* __restrict__ part_d,
                                                       const int* __restrict__ part_i,
                                                       float* __restrict__ out,
                                                       float* __restrict__ block_loss) {
    const int tid = threadIdx.x;
    const int pix = blockIdx.x * BLK + tid;

    float best_d = part_d[pix];
    int best_i = part_i[pix];
#pragma unroll
    for (int ch = 1; ch < NSUPER; ++ch) {
        float d = part_d[ch * NPIX + pix];
        int i = part_i[ch * NPIX + pix];
        if (d < best_d) { best_d = d; best_i = i; }  // strict <, ascending code ranges
    }

    const int b = pix >> 12;
    const int hw = pix & (HWSZ - 1);
    const float* zp = z + (long)b * BIMG + hw;
    const float* q = emb + (long)best_i * CDIM;
    float* op = out + (long)b * BIMG + hw;

    float lsum = 0.f;
#pragma unroll
    for (int c = 0; c < CDIM; ++c) {
        float zv = zp[c * HWSZ];
        float qv = q[c];
        float diff = qv - zv;
        op[c * HWSZ] = zv + diff;   // STE, reference roundings
        lsum += diff * diff;
    }

    out[(long)NPIX * CDIM + 1 + pix] = (float)best_i;

    __shared__ float red[BLK];
    red[tid] = lsum;
    __syncthreads();
    for (int s = BLK / 2; s > 0; s >>= 1) {
        if (tid < s) red[tid] += red[tid + s];
        __syncthreads();
    }
    if (tid == 0) block_loss[blockIdx.x] = red[0];
}

__global__ __launch_bounds__(128) void loss_kernel(const float* __restrict__ block_loss,
                                                   float* __restrict__ out) {
    __shared__ float red[128];
    const int tid = threadIdx.x;
    red[tid] = block_loss[tid];
    __syncthreads();
    for (int s = 64; s > 0; s >>= 1) {
        if (tid < s) red[tid] += red[tid + s];
        __syncthreads();
    }
    if (tid == 0) {
        float m = red[0] * (1.0f / (float)(NPIX * CDIM));
        out[(long)NPIX * CDIM] = m + 0.25f * m;
    }
}

extern "C" void kernel_launch(void* const* d_in, const int* in_sizes, int n_in,
                              void* d_out, int out_size, void* d_ws, size_t ws_size,
                              hipStream_t stream) {
    const float* z = (const float*)d_in[0];
    const float* emb = (const float*)d_in[1];
    float* out = (float*)d_out;

    char* ws = (char*)d_ws;
    float* part_d = (float*)ws;                                        // 512 KB
    int* part_i = (int*)(ws + (long)NSUPER * NPIX * 4);                // 512 KB
    float* esq = (float*)(ws + 2L * NSUPER * NPIX * 4);                // 32 KB
    float* zsq = (float*)(ws + 2L * NSUPER * NPIX * 4 + NE * 4);       // 128 KB
    float* block_loss = (float*)(ws + 2L * NSUPER * NPIX * 4 + NE * 4 + NPIX * 4);

    esq_kernel<<<NE / 256, 256, 0, stream>>>(emb, esq);
    zsq_kernel<<<NPIX / 256, 256, 0, stream>>>(z, zsq);

    dim3 gridB(NPIX / MB, NSUPER);
    dist_kernel<<<gridB, BLK, 0, stream>>>(z, emb, esq, zsq, part_d, part_i);

    finalize_kernel<<<NPIX / BLK, BLK, 0, stream>>>(z, emb, part_d, part_i, out, block_loss);

    loss_kernel<<<1, 128, 0, stream>>>(block_loss, out);
}